// Round 1
// baseline (245.945 us; speedup 1.0000x reference)
//
#include <hip/hip_runtime.h>

// LIF recurrence: u_t = decay*u_{t-1} + x_t - o_{t-1}*VTH ; o_t = (u_t - VTH > 0)
// x: [B=64, N=4096, T=100] f32, T contiguous. One thread per neuron (B*N threads),
// sequential over T in registers. float4 loads/stores along each neuron's own
// contiguous 400B row; full unroll keeps per-line accesses adjacent so each
// 128B line is fetched once and fully consumed.
//
// Exactness note: decay = 0.5 (power of two) and o*VTH in {0, 0.5} are exact
// products, so fp-contract cannot perturb u; spike compare matches reference
// bit-for-bit.

#define VTH 0.5f
#define T_STEPS 100

__global__ __launch_bounds__(256) void lif_kernel(const float* __restrict__ x,
                                                  const float* __restrict__ decay_p,
                                                  float* __restrict__ out,
                                                  int n_neurons) {
    const int neuron = blockIdx.x * blockDim.x + threadIdx.x;
    if (neuron >= n_neurons) return;

    const float decay = decay_p[0];

    const float4* __restrict__ xrow =
        (const float4*)(x + (size_t)neuron * T_STEPS);
    float4* __restrict__ orow = (float4*)(out + (size_t)neuron * T_STEPS);

    float u = 0.0f;
    float o = 0.0f;

#pragma unroll
    for (int i = 0; i < T_STEPS / 4; ++i) {
        float4 xv = xrow[i];
        float4 ov;
        u = decay * u + xv.x - o * VTH; o = (u > VTH) ? 1.0f : 0.0f; ov.x = o;
        u = decay * u + xv.y - o * VTH; o = (u > VTH) ? 1.0f : 0.0f; ov.y = o;
        u = decay * u + xv.z - o * VTH; o = (u > VTH) ? 1.0f : 0.0f; ov.z = o;
        u = decay * u + xv.w - o * VTH; o = (u > VTH) ? 1.0f : 0.0f; ov.w = o;
        orow[i] = ov;
    }
}

extern "C" void kernel_launch(void* const* d_in, const int* in_sizes, int n_in,
                              void* d_out, int out_size, void* d_ws, size_t ws_size,
                              hipStream_t stream) {
    const float* x = (const float*)d_in[0];
    const float* decay = (const float*)d_in[1];
    float* out = (float*)d_out;

    const int n_neurons = in_sizes[0] / T_STEPS;  // 64*4096 = 262144
    const int block = 256;
    const int grid = (n_neurons + block - 1) / block;

    lif_kernel<<<grid, block, 0, stream>>>(x, decay, out, n_neurons);
}

// Round 2
// 186.282 us; speedup vs baseline: 1.3203x; 1.3203x over previous
//
#include <hip/hip_runtime.h>

// LIF recurrence: u_t = decay*u_{t-1} + x_t - o_{t-1}*VTH ; o_t = (u_t - VTH > 0)
// x: [B=64, N=4096, T=100] f32, T contiguous (400 B per neuron row).
//
// R2 structure: 1-wave blocks (64 threads) own 64 consecutive neurons — a
// contiguous 25.6 KB slab of x. Stage slab into LDS via global_load_lds DMA
// (25 x 1KB wave-wide, fully coalesced, no VGPR round-trip), compute the
// recurrence in-place in LDS (x[j] dead once consumed -> overwrite with o[j]),
// then store back with coalesced 1KB wave-wide float4 stores.
// LDS 25.6 KB -> 6 blocks/CU; phases of independent blocks overlap.
//
// Exactness: decay=0.5 and o*VTH in {0,0.5} are exact products; spike compare
// is bit-deterministic vs the numpy reference (R1 absmax was 0.0).

#define VTH 0.5f
#define T_STEPS 100
#define W 64                  // neurons per block == threads per block (1 wave)
#define F4_PER_ROW 25         // 100 floats = 25 float4 per neuron

__global__ __launch_bounds__(64) void lif_kernel(const float* __restrict__ x,
                                                 const float* __restrict__ decay_p,
                                                 float* __restrict__ out,
                                                 int n_neurons) {
    __shared__ float lds[W * T_STEPS];   // 25,600 B flat mirror of this block's slab

    const int tid = threadIdx.x;
    const size_t block_f = (size_t)blockIdx.x * (W * T_STEPS);  // float offset of slab
    const float decay = decay_p[0];

    // ---- Stage: 25 wave-wide DMA loads, each 64 lanes x 16 B = 1 KB coalesced.
    // HW places lane i's 16 B at lds_base + i*16 -> flat slab copy.
    #pragma unroll
    for (int k = 0; k < F4_PER_ROW; ++k) {
        const float* gsrc = x + block_f + (size_t)(k * W + tid) * 4;
        __builtin_amdgcn_global_load_lds(
            (const __attribute__((address_space(1))) float*)gsrc,
            (__attribute__((address_space(3))) float*)&lds[k * W * 4],
            16, 0, 0);
    }
    __syncthreads();   // waits vmcnt(0): DMA complete

    // ---- Compute: thread t owns neuron (block*64 + t); row = float4s [t*25, t*25+25).
    // In-place overwrite x -> o.
    float4* lds4 = (float4*)lds;
    float u = 0.0f, o = 0.0f;
    #pragma unroll
    for (int i = 0; i < F4_PER_ROW; ++i) {
        float4 v = lds4[tid * F4_PER_ROW + i];
        u = decay * u + v.x - o * VTH; o = (u > VTH) ? 1.0f : 0.0f; v.x = o;
        u = decay * u + v.y - o * VTH; o = (u > VTH) ? 1.0f : 0.0f; v.y = o;
        u = decay * u + v.z - o * VTH; o = (u > VTH) ? 1.0f : 0.0f; v.z = o;
        u = decay * u + v.w - o * VTH; o = (u > VTH) ? 1.0f : 0.0f; v.w = o;
        lds4[tid * F4_PER_ROW + i] = v;
    }
    __syncthreads();

    // ---- Store: conflict-free LDS reads (lane-contiguous), coalesced 1 KB stores.
    float4* out4 = (float4*)(out + block_f);
    #pragma unroll
    for (int k = 0; k < F4_PER_ROW; ++k) {
        out4[k * W + tid] = lds4[k * W + tid];
    }
}

extern "C" void kernel_launch(void* const* d_in, const int* in_sizes, int n_in,
                              void* d_out, int out_size, void* d_ws, size_t ws_size,
                              hipStream_t stream) {
    const float* x = (const float*)d_in[0];
    const float* decay = (const float*)d_in[1];
    float* out = (float*)d_out;

    const int n_neurons = in_sizes[0] / T_STEPS;   // 262,144 (divisible by W)
    const int grid = n_neurons / W;                // 4096 blocks

    lif_kernel<<<grid, W, 0, stream>>>(x, decay, out, n_neurons);
}